// Round 9
// baseline (303.227 us; speedup 1.0000x reference)
//
#include <hip/hip_runtime.h>
#include <cstdint>
#include <cstddef>

// Dual attention (channel attention), B=16 S=512 D=1024 H=16 dk=64.
// Round 13. R12 (275.7us, best) showed gemm3 is staging-bound: across the
// two measured variants of the same 2-phase body, time ~ linear in staged
// bytes/K-step (32KB->76us, 48KB->102us; fit t = 24 + 1.63us/KB). So:
// shrink total staged bytes. gemm3 tile 256x128 (waves partition M):
// per 256x128 output, staged drops 96KB (2 blocks) -> 80KB (B staged once).
// Parameter change only -- same kt/kk order (bit-identical numerics), same
// async DMA staging, same swizzles (verified: row&15==arow, row&7==lane&7
// still hold with the new wave mapping). LDS 80KB -> 2 blocks/CU exactly.
// Everything else identical to R12.
// Fallback (pre-stated): gemm3 >= 102us or regression -> revert R12, declare.
// Pipeline:
//   1. pack_w: f32 -> fp16 weights (Wq,Wk,Wv,Wo)
//   2. gemm3 (z=3): Pq16,Pk16,Pv16 = f16(x@W^T+b), x = raw f32 q/k/v
//   3. scores: part[(b,slice),i*16+j] = sum_{s in slice,c} Qf Kf  (MFMA)
//   4. mix: per-block softmax(part sum, x0.25) -> Mm = I + beta*attn;
//      xmix[r,64i+c] = f16( sum_j Mm[i,j]*Pv16[r,64j+c] ); attn -> d_out
//   5. out = f16 GEMM(xmix, Wo^T) + bo -> d_out
// mask (d_in[3]) and adj (d_in[4]) are unused by the reference.

#define DIM 1024

typedef _Float16 f16_t;
typedef _Float16 f16x4_t __attribute__((ext_vector_type(4)));
typedef _Float16 f16x8_t __attribute__((ext_vector_type(8)));
typedef float    f32x4_t __attribute__((ext_vector_type(4)));

__device__ __forceinline__ void async_ld16(const void* g, void* l) {
    __builtin_amdgcn_global_load_lds((const __attribute__((address_space(1))) void*)g,
                                     (__attribute__((address_space(3))) void*)l,
                                     16, 0, 0);
}

// ---------------------------------------------------------------- pack_w
// Weights only, 32B/thread (float4 pairs): 4 x 131072 pairs = 524288
// = 2048 blocks exactly.
__global__ __launch_bounds__(256) void pack_w(
    const float* __restrict__ Wq, const float* __restrict__ Wk,
    const float* __restrict__ Wv, const float* __restrict__ Wo,
    f16_t* __restrict__ Bq, f16_t* __restrict__ Bk,
    f16_t* __restrict__ Bv, f16_t* __restrict__ Bo)
{
    const int u = blockIdx.x * 256 + threadIdx.x;
    const float* src; f16_t* dst; int i;
    if (u < 131072)       { src = Wq; dst = Bq; i = u; }
    else if (u < 262144)  { src = Wk; dst = Bk; i = u - 131072; }
    else if (u < 393216)  { src = Wv; dst = Bv; i = u - 262144; }
    else                  { src = Wo; dst = Bo; i = u - 393216; }
    float4 s0 = ((const float4*)src)[2 * i];
    float4 s1 = ((const float4*)src)[2 * i + 1];
    f16x8_t h;
    h[0] = (f16_t)s0.x; h[1] = (f16_t)s0.y; h[2] = (f16_t)s0.z; h[3] = (f16_t)s0.w;
    h[4] = (f16_t)s1.x; h[5] = (f16_t)s1.y; h[6] = (f16_t)s1.z; h[7] = (f16_t)s1.w;
    ((f16x8_t*)dst)[i] = h;
}

// ----------------------------------- projection GEMM, 256x128 (f32 A, DMA)
// C16[m,n] = f16( sum_k (f16)A[m,k] * B[n,k] + bias[n] ). A [8192,1024] f32
// raw input, B [1024,1024] f16 packed weights. Tile 256x128, BK=64, 4 waves
// partitioning M (wave w owns rows wm = w*64 .. +63; all 128 N cols).
// A staged f32 via global_load_lds: 16 issues/thread; LDS unit n = s*256+tid
// (row = n>>4 = s*16 + tid>>4, su = tid&15) holds global unit
// gu = su ^ (row&15). Reader: row = wm+mt*16+arow (row&15 == arow), units
// S = U ^ arow, f32->f16 RNE cvt in regs before MFMA (bit-identical to the
// old pack conversion). B staging/read byte-identical to the proven body.
// LDS 80KB (As32 64K + Bs 16K) = 2 blocks/CU exactly.
__device__ __forceinline__ void gemm_body_qkv(
    const float* __restrict__ A, const f16_t* __restrict__ B,
    const float* __restrict__ bias, f16_t* __restrict__ C16,
    float* As32, f16_t* Bs, int tileM, int tileN)
{
    const int tid  = threadIdx.x;
    const int lane = tid & 63;
    const int w    = tid >> 6;
    const int wm   = w << 6;                            // wave M base

    f32x4_t acc[4][8];
#pragma unroll
    for (int i = 0; i < 4; ++i)
#pragma unroll
        for (int j = 0; j < 8; ++j)
            acc[i][j] = (f32x4_t){0.f, 0.f, 0.f, 0.f};

    // B staging constants (proven body)
    const int srow = lane >> 3;
    const int scol = ((lane & 7) ^ (lane >> 3)) << 3;
    // A staging constants: issue s writes units n = s*256 + tid;
    // row = s*16 + rlo, su = tid&15, source unit gu = su ^ (row&15).
    const int rlo = tid >> 4;                           // row&15, s-independent
    const int gu  = (tid & 15) ^ rlo;                   // global 16B-unit
    const float* srcA0 = A + (size_t)(tileM + rlo) * DIM + (gu << 2);
    // fragment-read constants
    const int arow = lane & 15;
    const int kqu  = lane >> 4;
    const int sx   = lane & 7;

    for (int kt = 0; kt < 16; ++kt) {
        const int k0 = kt << 6;                         // elems (f32 A, f16 B)
#pragma unroll
        for (int t4 = 0; t4 < 4; ++t4) {                // B: 16KB f16
            const int row = (w << 5) + (t4 << 3);
            async_ld16(B + (size_t)(tileN + row + srow) * DIM + k0 + scol,
                       (void*)(Bs + row * 64));
        }
#pragma unroll
        for (int s = 0; s < 16; ++s)                    // A: 64KB f32
            async_ld16(srcA0 + (size_t)(s << 4) * DIM + k0,
                       (void*)(As32 + (s << 10) + (tid << 2)));
        __syncthreads();
#pragma unroll
        for (int kk = 0; kk < 2; ++kk) {
            const int cu = ((kk << 2) + kqu) ^ sx;      // B swizzled unit
            const int U0 = (kk << 3) + (kqu << 1);      // A units (2 per frag)
            const int S0 = U0 ^ arow;
            const int S1 = (U0 + 1) ^ arow;
            f16x8_t af[4], bfv[8];
#pragma unroll
            for (int mt = 0; mt < 4; ++mt) {
                const float* rb = As32 + (wm + (mt << 4) + arow) * 64;
                f32x4_t lo = *(const f32x4_t*)(rb + (S0 << 2));
                f32x4_t hi = *(const f32x4_t*)(rb + (S1 << 2));
                f16x8_t h;
                h[0] = (f16_t)lo[0]; h[1] = (f16_t)lo[1];
                h[2] = (f16_t)lo[2]; h[3] = (f16_t)lo[3];
                h[4] = (f16_t)hi[0]; h[5] = (f16_t)hi[1];
                h[6] = (f16_t)hi[2]; h[7] = (f16_t)hi[3];
                af[mt] = h;
            }
#pragma unroll
            for (int nt = 0; nt < 8; ++nt)
                bfv[nt] = *(const f16x8_t*)(Bs + ((nt << 4) + arow) * 64 + (cu << 3));
#pragma unroll
            for (int mt = 0; mt < 4; ++mt)
#pragma unroll
                for (int nt = 0; nt < 8; ++nt)
                    acc[mt][nt] = __builtin_amdgcn_mfma_f32_16x16x32_f16(
                        af[mt], bfv[nt], acc[mt][nt], 0, 0, 0);
        }
        __syncthreads();
    }

    // C/D layout: col = lane&15, row = (lane>>4)*4 + reg
    const int rq = (lane >> 4) << 2;
#pragma unroll
    for (int nt = 0; nt < 8; ++nt) {
        const int col = tileN + (nt << 4) + arow;
        const float bv = bias[col];
#pragma unroll
        for (int mt = 0; mt < 4; ++mt) {
            const int row = tileM + wm + (mt << 4) + rq;
#pragma unroll
            for (int r = 0; r < 4; ++r)
                C16[(size_t)(row + r) * DIM + col] = (f16_t)(acc[mt][nt][r] + bv);
        }
    }
}

struct Gemm3Args {
    const float* A[3];    // raw f32 q, k, v
    const f16_t* B[3];    // packed f16 weights
    const float* bias[3];
    f16_t*       C16[3];  // Pq16, Pk16, Pv16
};

// three projection GEMMs in one launch: grid (32, 8, 3) = 768 blocks
__global__ __launch_bounds__(256, 2) void gemm3(Gemm3Args args)
{
    __shared__ __align__(16) float As32[256 * 64];   // 64KB
    __shared__ __align__(16) f16_t Bs[128 * 64];     // 16KB
    const int z = blockIdx.z;
    gemm_body_qkv(args.A[z], args.B[z], args.bias[z], args.C16[z],
                  As32, Bs, blockIdx.x * 256, blockIdx.y * 128);
}

// ---------------------------------------------------------------- gemm_o
// R0-proven all-f16 body (both operands via global_load_lds), f32 out.
__global__ __launch_bounds__(256) void gemm_o(
    const f16_t* __restrict__ A, const f16_t* __restrict__ B,
    const float* __restrict__ bias, float* __restrict__ C)
{
    __shared__ __align__(16) f16_t As[128 * 64];
    __shared__ __align__(16) f16_t Bs[128 * 64];
    const int tileM = blockIdx.x * 128, tileN = blockIdx.y * 128;
    const int tid  = threadIdx.x;
    const int lane = tid & 63;
    const int w    = tid >> 6;
    const int wm = (w & 1) << 6;
    const int wn = (w >> 1) << 6;

    f32x4_t acc[4][4];
#pragma unroll
    for (int i = 0; i < 4; ++i)
#pragma unroll
        for (int j = 0; j < 4; ++j)
            acc[i][j] = (f32x4_t){0.f, 0.f, 0.f, 0.f};

    const int srow = lane >> 3;
    const int scol = ((lane & 7) ^ (lane >> 3)) << 3;
    const int arow = lane & 15;
    const int sx   = lane & 7;
    const int kqu  = lane >> 4;

    for (int kt = 0; kt < 16; ++kt) {
        const int k0 = kt << 6;
#pragma unroll
        for (int t4 = 0; t4 < 4; ++t4) {
            const int row = (w << 5) + (t4 << 3);
            async_ld16(A + (size_t)(tileM + row + srow) * DIM + k0 + scol,
                       (void*)(As + row * 64));
            async_ld16(B + (size_t)(tileN + row + srow) * DIM + k0 + scol,
                       (void*)(Bs + row * 64));
        }
        __syncthreads();
#pragma unroll
        for (int kk = 0; kk < 2; ++kk) {
            const int cu = ((kk << 2) + kqu) ^ sx;
            f16x8_t af[4], bfv[4];
#pragma unroll
            for (int mt = 0; mt < 4; ++mt)
                af[mt] = *(const f16x8_t*)(As + (wm + (mt << 4) + arow) * 64 + (cu << 3));
#pragma unroll
            for (int nt = 0; nt < 4; ++nt)
                bfv[nt] = *(const f16x8_t*)(Bs + (wn + (nt << 4) + arow) * 64 + (cu << 3));
#pragma unroll
            for (int mt = 0; mt < 4; ++mt)
#pragma unroll
                for (int nt = 0; nt < 4; ++nt)
                    acc[mt][nt] = __builtin_amdgcn_mfma_f32_16x16x32_f16(
                        af[mt], bfv[nt], acc[mt][nt], 0, 0, 0);
        }
        __syncthreads();
    }

    const int rq = (lane >> 4) << 2;
#pragma unroll
    for (int nt = 0; nt < 4; ++nt) {
        const int col = tileN + wn + (nt << 4) + arow;
        const float bv = bias[col];
#pragma unroll
        for (int mt = 0; mt < 4; ++mt) {
            const int row = tileM + wm + (mt << 4) + rq;
#pragma unroll
            for (int r = 0; r < 4; ++r)
                C[(size_t)(row + r) * DIM + col] = acc[mt][nt][r] + bv;
        }
    }
}

// ---------------------------------------------------------------- scores
// part[(b*16+slice)*256 + i*16+j] = sum_{s in slice, c} Qf[b,i,s*64+c] *
// Kf[b,j,s*64+c]. Grid (16 b, 16 slices) = 256 blocks; wave w owns rows
// s = slice*32 + w*8 .. +7. No atomics, no fences (R7/R8 lesson).
__global__ __launch_bounds__(256) void scores_kernel(
    const f16_t* __restrict__ Pq16, const f16_t* __restrict__ Pk16,
    float* __restrict__ part)
{
    __shared__ float red[4][256];
    const int b = blockIdx.x;
    const int slice = blockIdx.y;
    const int lane = threadIdx.x & 63;
    const int w = threadIdx.x >> 6;
    const int m  = lane & 15;              // i (A rows) / j (B rows)
    const int q8 = (lane >> 4) << 3;       // k-offset within 32-chunk

    f32x4_t acc = (f32x4_t){0.f, 0.f, 0.f, 0.f};
    const int s0 = slice * 32 + w * 8;
#pragma unroll
    for (int ss = 0; ss < 8; ++ss) {
        const size_t rb = (size_t)(b * 512 + s0 + ss) * DIM;
        const f16_t* qrow = Pq16 + rb;
        const f16_t* krow = Pk16 + rb;
#pragma unroll
        for (int c0 = 0; c0 < 64; c0 += 32) {
            f16x8_t af = *(const f16x8_t*)(qrow + m * 64 + c0 + q8);
            f16x8_t bf = *(const f16x8_t*)(krow + m * 64 + c0 + q8);
            acc = __builtin_amdgcn_mfma_f32_16x16x32_f16(af, bf, acc, 0, 0, 0);
        }
    }
    // C/D: col(j) = lane&15, row(i) = (lane>>4)*4 + r
    const int rq = (lane >> 4) << 2;
#pragma unroll
    for (int r = 0; r < 4; ++r)
        red[w][(rq + r) * 16 + m] = acc[r];
    __syncthreads();
    const int t = threadIdx.x;
    part[(size_t)(b * 16 + slice) * 256 + t] =
        red[0][t] + red[1][t] + red[2][t] + red[3][t];
}

// ------------------------------------------------- channel mix (+softmax)
// Each block computes its batch's softmax from part redundantly (L2-hot,
// threads 0..15: thread i owns row i), builds Mm = I + beta*attn in LDS,
// then mixes with vectorized 16B/lane V loads: thread t = (rloc=t>>4,
// i8=(t>>3)&1, u=t&7); r = blk*16+rloc; v[j] = Pv16[r, j*64+u*8..+7];
// xmix[r, i*64+u*8+c] = f16( sum_j Msh[i*16+j]*v[j][c] ), i in i8*8..+7.
// Grid 512 blocks x 16 rows. One block per batch (blockIdx.x%32==0)
// writes attn to d_out.
__global__ __launch_bounds__(256) void mix_kernel(
    const f16_t* __restrict__ Pv16, const float* __restrict__ part,
    const float* __restrict__ beta_p,
    float* __restrict__ attn_out, f16_t* __restrict__ xmix)
{
    __shared__ float Msh[256];
    const int rbase = blockIdx.x * 16;
    const int b = blockIdx.x >> 5;         // 32 blocks per batch
    const int t = threadIdx.x;
    if (t < 16) {
        const int i = t;
        float s[16];
#pragma unroll
        for (int j = 0; j < 16; ++j) s[j] = 0.f;
#pragma unroll 4
        for (int sl = 0; sl < 16; ++sl) {
            const float* pp = part + (size_t)(b * 16 + sl) * 256 + i * 16;
#pragma unroll
            for (int j4 = 0; j4 < 4; ++j4) {
                float4 v4 = ((const float4*)pp)[j4];
                s[j4 * 4 + 0] += v4.x; s[j4 * 4 + 1] += v4.y;
                s[j4 * 4 + 2] += v4.z; s[j4 * 4 + 3] += v4.w;
            }
        }
        float mx = -1e30f;
#pragma unroll
        for (int j = 0; j < 16; ++j) {
            s[j] *= 0.25f;                 // 1/sqrt(h), h=16
            mx = fmaxf(mx, s[j]);
        }
        float sum = 0.f;
#pragma unroll
        for (int j = 0; j < 16; ++j) { s[j] = expf(s[j] - mx); sum += s[j]; }
        const float inv = 1.f / sum;
        const float beta = beta_p[0];
        const bool wr_attn = (blockIdx.x & 31) == 0;
#pragma unroll
        for (int j = 0; j < 16; ++j) {
            float a = s[j] * inv;
            if (wr_attn) attn_out[(b * 16 + i) * 16 + j] = a;
            Msh[i * 16 + j] = beta * a + ((j == i) ? 1.f : 0.f);
        }
    }
    __syncthreads();
    const int u    = t & 7;                // 8-channel unit within head
    const int i8   = (t >> 3) & 1;         // i half (0: i=0..7, 1: i=8..15)
    const int rloc = t >> 4;               // row within block (0..15)
    const int r = rbase + rloc;
    const f16_t* vrow = Pv16 + (size_t)r * DIM + u * 8;
    f16x8_t v[16];
#pragma unroll
    for (int j = 0; j < 16; ++j)
        v[j] = *(const f16x8_t*)(vrow + j * 64);
    f16_t* orow = xmix + (size_t)r * DIM + u * 8;
#pragma unroll
    for (int ii = 0; ii < 8; ++ii) {
        const int i = i8 * 8 + ii;
        const float* mrow = Msh + i * 16;
        float acc[8];
#pragma unroll
        for (int c = 0; c < 8; ++c) acc[c] = 0.f;
#pragma unroll
        for (int j = 0; j < 16; ++j) {
            const float m = mrow[j];
#pragma unroll
            for (int c = 0; c < 8; ++c)
                acc[c] += m * (float)v[j][c];   // v_fma_mix
        }
        f16x8_t o;
#pragma unroll
        for (int c = 0; c < 8; ++c) o[c] = (f16_t)acc[c];
        *(f16x8_t*)(orow + i * 64) = o;
    }
}

// ---------------------------------------------------------------- launch
extern "C" void kernel_launch(void* const* d_in, const int* in_sizes, int n_in,
                              void* d_out, int out_size, void* d_ws, size_t ws_size,
                              hipStream_t stream)
{
    (void)in_sizes; (void)n_in; (void)out_size; (void)ws_size;
    const float* q    = (const float*)d_in[0];
    const float* k    = (const float*)d_in[1];
    const float* v    = (const float*)d_in[2];
    // d_in[3] mask, d_in[4] adj: unused by reference
    const float* Wq   = (const float*)d_in[5];
    const float* bq   = (const float*)d_in[6];
    const float* Wk   = (const float*)d_in[7];
    const float* bk   = (const float*)d_in[8];
    const float* Wv   = (const float*)d_in[9];
    const float* bv   = (const float*)d_in[10];
    const float* Wo   = (const float*)d_in[11];
    const float* bo   = (const float*)d_in[12];
    const float* beta = (const float*)d_in[13];

    float* out  = (float*)d_out;                     // [8192,1024]
    float* attn = (float*)d_out + 8388608;           // [16,16,16]

    char* p = (char*)d_ws;
    auto take = [&](size_t n) -> char* {
        char* cur = p; p += (n + 255) & ~(size_t)255; return cur;
    };
    f16_t* Bq = (f16_t*)take(2097152);
    f16_t* Bk = (f16_t*)take(2097152);
    f16_t* Bv = (f16_t*)take(2097152);
    f16_t* Bo = (f16_t*)take(2097152);
    f16_t* Pq16 = (f16_t*)take(16777216);
    f16_t* Pk16 = (f16_t*)take(16777216);
    f16_t* Pv16 = (f16_t*)take(16777216);
    f16_t* xmix = (f16_t*)take(16777216);
    float* part = (float*)take(262144);              // 16x16x256 partials

    pack_w<<<2048, 256, 0, stream>>>(Wq, Wk, Wv, Wo, Bq, Bk, Bv, Bo);

    Gemm3Args ga;
    ga.A[0] = q; ga.A[1] = k; ga.A[2] = v;
    ga.B[0] = Bq; ga.B[1] = Bk; ga.B[2] = Bv;
    ga.bias[0] = bq; ga.bias[1] = bk; ga.bias[2] = bv;
    ga.C16[0] = Pq16; ga.C16[1] = Pk16; ga.C16[2] = Pv16;
    gemm3<<<dim3(32, 8, 3), 256, 0, stream>>>(ga);

    scores_kernel<<<dim3(16, 16), 256, 0, stream>>>(Pq16, Pk16, part);
    mix_kernel<<<512, 256, 0, stream>>>(Pv16, part, beta, attn, xmix);
    gemm_o<<<dim3(64, 8), 256, 0, stream>>>(xmix, Bo, bo, out);
}

// Round 10
// 274.463 us; speedup vs baseline: 1.1048x; 1.1048x over previous
//
#include <hip/hip_runtime.h>
#include <cstdint>
#include <cstddef>

// Dual attention (channel attention), B=16 S=512 D=1024 H=16 dk=64.
// Round 14: REVERT to R12 (275.7us session best) per R13's pre-stated
// fallback. R13 (256x128 tile, 80KB LDS) regressed gemm3 102->127us:
// the staged-bytes linear model omitted occupancy -- 80KB LDS = 2
// blocks/CU (vs R12's 3), losing the inter-block staging/compute overlap
// that carries the 2-phase body (HBM BW fell 1448->985 GB/s despite
// FETCH dropping 95->74MB). Lesson: staged-byte trades only valid at
// constant blocks/CU. Restructure scorecard final: 0/4.
// This is the terminal kernel: gemm3 at the staging-bound floor of the
// only winning structure; gemm_o at the proven ceiling; pack_w/scores/mix
// at BW/latency floors; ~130us of the total is harness-fixed overhead.
// Pipeline:
//   1. pack_w: f32 -> fp16 weights (Wq,Wk,Wv,Wo)
//   2. gemm3 (z=3): Pq16,Pk16,Pv16 = f16(x@W^T+b), x = raw f32 q/k/v
//      (A staged as raw f32 via async global_load_lds, f32->f16 RNE cvt
//       in registers after ds_read -- bit-identical to a pack conversion)
//   3. scores: part[(b,slice),i*16+j] = sum_{s in slice,c} Qf Kf  (MFMA)
//   4. mix: per-block softmax(part sum, x0.25) -> Mm = I + beta*attn;
//      xmix[r,64i+c] = f16( sum_j Mm[i,j]*Pv16[r,64j+c] ); attn -> d_out
//   5. out = f16 GEMM(xmix, Wo^T) + bo -> d_out
// mask (d_in[3]) and adj (d_in[4]) are unused by the reference.

#define DIM 1024

typedef _Float16 f16_t;
typedef _Float16 f16x4_t __attribute__((ext_vector_type(4)));
typedef _Float16 f16x8_t __attribute__((ext_vector_type(8)));
typedef float    f32x4_t __attribute__((ext_vector_type(4)));

__device__ __forceinline__ void async_ld16(const void* g, void* l) {
    __builtin_amdgcn_global_load_lds((const __attribute__((address_space(1))) void*)g,
                                     (__attribute__((address_space(3))) void*)l,
                                     16, 0, 0);
}

// ---------------------------------------------------------------- pack_w
// Weights only, 32B/thread (float4 pairs): 4 x 131072 pairs = 524288
// = 2048 blocks exactly.
__global__ __launch_bounds__(256) void pack_w(
    const float* __restrict__ Wq, const float* __restrict__ Wk,
    const float* __restrict__ Wv, const float* __restrict__ Wo,
    f16_t* __restrict__ Bq, f16_t* __restrict__ Bk,
    f16_t* __restrict__ Bv, f16_t* __restrict__ Bo)
{
    const int u = blockIdx.x * 256 + threadIdx.x;
    const float* src; f16_t* dst; int i;
    if (u < 131072)       { src = Wq; dst = Bq; i = u; }
    else if (u < 262144)  { src = Wk; dst = Bk; i = u - 131072; }
    else if (u < 393216)  { src = Wv; dst = Bv; i = u - 262144; }
    else                  { src = Wo; dst = Bo; i = u - 393216; }
    float4 s0 = ((const float4*)src)[2 * i];
    float4 s1 = ((const float4*)src)[2 * i + 1];
    f16x8_t h;
    h[0] = (f16_t)s0.x; h[1] = (f16_t)s0.y; h[2] = (f16_t)s0.z; h[3] = (f16_t)s0.w;
    h[4] = (f16_t)s1.x; h[5] = (f16_t)s1.y; h[6] = (f16_t)s1.z; h[7] = (f16_t)s1.w;
    ((f16x8_t*)dst)[i] = h;
}

// ------------------------------------------- projection GEMM (f32 A, DMA)
// C16[m,n] = f16( sum_k (f16)A[m,k] * B[n,k] + bias[n] ). A [8192,1024] f32
// raw input, B [1024,1024] f16 packed weights. Tile 128x128, BK=64, 4 waves.
// A staged as f32 via global_load_lds (async, 8 issues/thread/K-step);
// f32->f16 RNE conversion in registers after ds_read (bit-identical to the
// old pack path). B staging/read path byte-identical to the proven body.
// LDS 48KB (As32 32K + Bs 16K) = 3 blocks/CU (the overlap that carries
// the 2-phase body -- see R13 post-mortem).
__device__ __forceinline__ void gemm_body_qkv(
    const float* __restrict__ A, const f16_t* __restrict__ B,
    const float* __restrict__ bias, f16_t* __restrict__ C16,
    float* As32, f16_t* Bs, int tileM, int tileN)
{
    const int tid  = threadIdx.x;
    const int lane = tid & 63;
    const int w    = tid >> 6;
    const int wm = (w & 1) << 6;
    const int wn = (w >> 1) << 6;

    f32x4_t acc[4][4];
#pragma unroll
    for (int i = 0; i < 4; ++i)
#pragma unroll
        for (int j = 0; j < 4; ++j)
            acc[i][j] = (f32x4_t){0.f, 0.f, 0.f, 0.f};

    // B staging constants (proven body)
    const int srow = lane >> 3;
    const int scol = ((lane & 7) ^ (lane >> 3)) << 3;
    // A staging constants: issue s writes units n = s*256 + w*64 + lane;
    // row = n>>4 = s*16 + rlo, su = lane&15, source unit gu = su ^ (row&15).
    const int rlo = (w << 2) + (lane >> 4);             // row&15, s-independent
    const int gu  = (lane & 15) ^ rlo;                  // global 16B-unit
    const float* srcA0 = A + (size_t)(tileM + rlo) * DIM + (gu << 2);
    // fragment-read constants
    const int arow = lane & 15;
    const int kqu  = lane >> 4;
    const int sx   = lane & 7;

    for (int kt = 0; kt < 16; ++kt) {
        const int k0 = kt << 6;                         // elems (f32 A, f16 B)
#pragma unroll
        for (int t4 = 0; t4 < 4; ++t4) {                // B: 16KB f16
            const int row = (w << 5) + (t4 << 3);
            async_ld16(B + (size_t)(tileN + row + srow) * DIM + k0 + scol,
                       (void*)(Bs + row * 64));
        }
#pragma unroll
        for (int s = 0; s < 8; ++s)                     // A: 32KB f32
            async_ld16(srcA0 + (size_t)(s << 4) * DIM + k0,
                       (void*)(As32 + (s << 10) + (w << 8)));
        __syncthreads();
#pragma unroll
        for (int kk = 0; kk < 2; ++kk) {
            const int cu = ((kk << 2) + kqu) ^ sx;      // B swizzled unit
            const int U0 = (kk << 3) + (kqu << 1);      // A units (2 per frag)
            const int S0 = U0 ^ arow;
            const int S1 = (U0 + 1) ^ arow;
            f16x8_t af[4], bfv[4];
#pragma unroll
            for (int mt = 0; mt < 4; ++mt) {
                const float* rb = As32 + (wm + (mt << 4) + arow) * 64;
                f32x4_t lo = *(const f32x4_t*)(rb + (S0 << 2));
                f32x4_t hi = *(const f32x4_t*)(rb + (S1 << 2));
                f16x8_t h;
                h[0] = (f16_t)lo[0]; h[1] = (f16_t)lo[1];
                h[2] = (f16_t)lo[2]; h[3] = (f16_t)lo[3];
                h[4] = (f16_t)hi[0]; h[5] = (f16_t)hi[1];
                h[6] = (f16_t)hi[2]; h[7] = (f16_t)hi[3];
                af[mt] = h;
            }
#pragma unroll
            for (int nt = 0; nt < 4; ++nt)
                bfv[nt] = *(const f16x8_t*)(Bs + (wn + (nt << 4) + arow) * 64 + (cu << 3));
#pragma unroll
            for (int mt = 0; mt < 4; ++mt)
#pragma unroll
                for (int nt = 0; nt < 4; ++nt)
                    acc[mt][nt] = __builtin_amdgcn_mfma_f32_16x16x32_f16(
                        af[mt], bfv[nt], acc[mt][nt], 0, 0, 0);
        }
        __syncthreads();
    }

    // C/D layout: col = lane&15, row = (lane>>4)*4 + reg
    const int rq = (lane >> 4) << 2;
#pragma unroll
    for (int nt = 0; nt < 4; ++nt) {
        const int col = tileN + wn + (nt << 4) + arow;
        const float bv = bias[col];
#pragma unroll
        for (int mt = 0; mt < 4; ++mt) {
            const int row = tileM + wm + (mt << 4) + rq;
#pragma unroll
            for (int r = 0; r < 4; ++r)
                C16[(size_t)(row + r) * DIM + col] = (f16_t)(acc[mt][nt][r] + bv);
        }
    }
}

struct Gemm3Args {
    const float* A[3];    // raw f32 q, k, v
    const f16_t* B[3];    // packed f16 weights
    const float* bias[3];
    f16_t*       C16[3];  // Pq16, Pk16, Pv16
};

// three projection GEMMs in one launch: grid (64, 8, 3) = 1536 blocks
__global__ __launch_bounds__(256) void gemm3(Gemm3Args args)
{
    __shared__ __align__(16) float As32[128 * 64];   // 32KB
    __shared__ __align__(16) f16_t Bs[128 * 64];     // 16KB
    const int z = blockIdx.z;
    gemm_body_qkv(args.A[z], args.B[z], args.bias[z], args.C16[z],
                  As32, Bs, blockIdx.x * 128, blockIdx.y * 128);
}

// ---------------------------------------------------------------- gemm_o
// R0-proven all-f16 body (both operands via global_load_lds), f32 out.
__global__ __launch_bounds__(256) void gemm_o(
    const f16_t* __restrict__ A, const f16_t* __restrict__ B,
    const float* __restrict__ bias, float* __restrict__ C)
{
    __shared__ __align__(16) f16_t As[128 * 64];
    __shared__ __align__(16) f16_t Bs[128 * 64];
    const int tileM = blockIdx.x * 128, tileN = blockIdx.y * 128;
    const int tid  = threadIdx.x;
    const int lane = tid & 63;
    const int w    = tid >> 6;
    const int wm = (w & 1) << 6;
    const int wn = (w >> 1) << 6;

    f32x4_t acc[4][4];
#pragma unroll
    for (int i = 0; i < 4; ++i)
#pragma unroll
        for (int j = 0; j < 4; ++j)
            acc[i][j] = (f32x4_t){0.f, 0.f, 0.f, 0.f};

    const int srow = lane >> 3;
    const int scol = ((lane & 7) ^ (lane >> 3)) << 3;
    const int arow = lane & 15;
    const int sx   = lane & 7;
    const int kqu  = lane >> 4;

    for (int kt = 0; kt < 16; ++kt) {
        const int k0 = kt << 6;
#pragma unroll
        for (int t4 = 0; t4 < 4; ++t4) {
            const int row = (w << 5) + (t4 << 3);
            async_ld16(A + (size_t)(tileM + row + srow) * DIM + k0 + scol,
                       (void*)(As + row * 64));
            async_ld16(B + (size_t)(tileN + row + srow) * DIM + k0 + scol,
                       (void*)(Bs + row * 64));
        }
        __syncthreads();
#pragma unroll
        for (int kk = 0; kk < 2; ++kk) {
            const int cu = ((kk << 2) + kqu) ^ sx;
            f16x8_t af[4], bfv[4];
#pragma unroll
            for (int mt = 0; mt < 4; ++mt)
                af[mt] = *(const f16x8_t*)(As + (wm + (mt << 4) + arow) * 64 + (cu << 3));
#pragma unroll
            for (int nt = 0; nt < 4; ++nt)
                bfv[nt] = *(const f16x8_t*)(Bs + (wn + (nt << 4) + arow) * 64 + (cu << 3));
#pragma unroll
            for (int mt = 0; mt < 4; ++mt)
#pragma unroll
                for (int nt = 0; nt < 4; ++nt)
                    acc[mt][nt] = __builtin_amdgcn_mfma_f32_16x16x32_f16(
                        af[mt], bfv[nt], acc[mt][nt], 0, 0, 0);
        }
        __syncthreads();
    }

    const int rq = (lane >> 4) << 2;
#pragma unroll
    for (int nt = 0; nt < 4; ++nt) {
        const int col = tileN + wn + (nt << 4) + arow;
        const float bv = bias[col];
#pragma unroll
        for (int mt = 0; mt < 4; ++mt) {
            const int row = tileM + wm + (mt << 4) + rq;
#pragma unroll
            for (int r = 0; r < 4; ++r)
                C[(size_t)(row + r) * DIM + col] = acc[mt][nt][r] + bv;
        }
    }
}

// ---------------------------------------------------------------- scores
// part[(b*16+slice)*256 + i*16+j] = sum_{s in slice, c} Qf[b,i,s*64+c] *
// Kf[b,j,s*64+c]. Grid (16 b, 16 slices) = 256 blocks; wave w owns rows
// s = slice*32 + w*8 .. +7. No atomics, no fences (R7/R8 lesson).
__global__ __launch_bounds__(256) void scores_kernel(
    const f16_t* __restrict__ Pq16, const f16_t* __restrict__ Pk16,
    float* __restrict__ part)
{
    __shared__ float red[4][256];
    const int b = blockIdx.x;
    const int slice = blockIdx.y;
    const int lane = threadIdx.x & 63;
    const int w = threadIdx.x >> 6;
    const int m  = lane & 15;              // i (A rows) / j (B rows)
    const int q8 = (lane >> 4) << 3;       // k-offset within 32-chunk

    f32x4_t acc = (f32x4_t){0.f, 0.f, 0.f, 0.f};
    const int s0 = slice * 32 + w * 8;
#pragma unroll
    for (int ss = 0; ss < 8; ++ss) {
        const size_t rb = (size_t)(b * 512 + s0 + ss) * DIM;
        const f16_t* qrow = Pq16 + rb;
        const f16_t* krow = Pk16 + rb;
#pragma unroll
        for (int c0 = 0; c0 < 64; c0 += 32) {
            f16x8_t af = *(const f16x8_t*)(qrow + m * 64 + c0 + q8);
            f16x8_t bf = *(const f16x8_t*)(krow + m * 64 + c0 + q8);
            acc = __builtin_amdgcn_mfma_f32_16x16x32_f16(af, bf, acc, 0, 0, 0);
        }
    }
    // C/D: col(j) = lane&15, row(i) = (lane>>4)*4 + r
    const int rq = (lane >> 4) << 2;
#pragma unroll
    for (int r = 0; r < 4; ++r)
        red[w][(rq + r) * 16 + m] = acc[r];
    __syncthreads();
    const int t = threadIdx.x;
    part[(size_t)(b * 16 + slice) * 256 + t] =
        red[0][t] + red[1][t] + red[2][t] + red[3][t];
}

// ------------------------------------------------- channel mix (+softmax)
// Each block computes its batch's softmax from part redundantly (L2-hot,
// threads 0..15: thread i owns row i), builds Mm = I + beta*attn in LDS,
// then mixes with vectorized 16B/lane V loads: thread t = (rloc=t>>4,
// i8=(t>>3)&1, u=t&7); r = blk*16+rloc; v[j] = Pv16[r, j*64+u*8..+7];
// xmix[r, i*64+u*8+c] = f16( sum_j Msh[i*16+j]*v[j][c] ), i in i8*8..+7.
// Grid 512 blocks x 16 rows. One block per batch (blockIdx.x%32==0)
// writes attn to d_out.
__global__ __launch_bounds__(256) void mix_kernel(
    const f16_t* __restrict__ Pv16, const float* __restrict__ part,
    const float* __restrict__ beta_p,
    float* __restrict__ attn_out, f16_t* __restrict__ xmix)
{
    __shared__ float Msh[256];
    const int rbase = blockIdx.x * 16;
    const int b = blockIdx.x >> 5;         // 32 blocks per batch
    const int t = threadIdx.x;
    if (t < 16) {
        const int i = t;
        float s[16];
#pragma unroll
        for (int j = 0; j < 16; ++j) s[j] = 0.f;
#pragma unroll 4
        for (int sl = 0; sl < 16; ++sl) {
            const float* pp = part + (size_t)(b * 16 + sl) * 256 + i * 16;
#pragma unroll
            for (int j4 = 0; j4 < 4; ++j4) {
                float4 v4 = ((const float4*)pp)[j4];
                s[j4 * 4 + 0] += v4.x; s[j4 * 4 + 1] += v4.y;
                s[j4 * 4 + 2] += v4.z; s[j4 * 4 + 3] += v4.w;
            }
        }
        float mx = -1e30f;
#pragma unroll
        for (int j = 0; j < 16; ++j) {
            s[j] *= 0.25f;                 // 1/sqrt(h), h=16
            mx = fmaxf(mx, s[j]);
        }
        float sum = 0.f;
#pragma unroll
        for (int j = 0; j < 16; ++j) { s[j] = expf(s[j] - mx); sum += s[j]; }
        const float inv = 1.f / sum;
        const float beta = beta_p[0];
        const bool wr_attn = (blockIdx.x & 31) == 0;
#pragma unroll
        for (int j = 0; j < 16; ++j) {
            float a = s[j] * inv;
            if (wr_attn) attn_out[(b * 16 + i) * 16 + j] = a;
            Msh[i * 16 + j] = beta * a + ((j == i) ? 1.f : 0.f);
        }
    }
    __syncthreads();
    const int u    = t & 7;                // 8-channel unit within head
    const int i8   = (t >> 3) & 1;         // i half (0: i=0..7, 1: i=8..15)
    const int rloc = t >> 4;               // row within block (0..15)
    const int r = rbase + rloc;
    const f16_t* vrow = Pv16 + (size_t)r * DIM + u * 8;
    f16x8_t v[16];
#pragma unroll
    for (int j = 0; j < 16; ++j)
        v[j] = *(const f16x8_t*)(vrow + j * 64);
    f16_t* orow = xmix + (size_t)r * DIM + u * 8;
#pragma unroll
    for (int ii = 0; ii < 8; ++ii) {
        const int i = i8 * 8 + ii;
        const float* mrow = Msh + i * 16;
        float acc[8];
#pragma unroll
        for (int c = 0; c < 8; ++c) acc[c] = 0.f;
#pragma unroll
        for (int j = 0; j < 16; ++j) {
            const float m = mrow[j];
#pragma unroll
            for (int c = 0; c < 8; ++c)
                acc[c] += m * (float)v[j][c];   // v_fma_mix
        }
        f16x8_t o;
#pragma unroll
        for (int c = 0; c < 8; ++c) o[c] = (f16_t)acc[c];
        *(f16x8_t*)(orow + i * 64) = o;
    }
}

// ---------------------------------------------------------------- launch
extern "C" void kernel_launch(void* const* d_in, const int* in_sizes, int n_in,
                              void* d_out, int out_size, void* d_ws, size_t ws_size,
                              hipStream_t stream)
{
    (void)in_sizes; (void)n_in; (void)out_size; (void)ws_size;
    const float* q    = (const float*)d_in[0];
    const float* k    = (const float*)d_in[1];
    const float* v    = (const float*)d_in[2];
    // d_in[3] mask, d_in[4] adj: unused by reference
    const float* Wq   = (const float*)d_in[5];
    const float* bq   = (const float*)d_in[6];
    const float* Wk   = (const float*)d_in[7];
    const float* bk   = (const float*)d_in[8];
    const float* Wv   = (const float*)d_in[9];
    const float* bv   = (const float*)d_in[10];
    const float* Wo   = (const float*)d_in[11];
    const float* bo   = (const float*)d_in[12];
    const float* beta = (const float*)d_in[13];

    float* out  = (float*)d_out;                     // [8192,1024]
    float* attn = (float*)d_out + 8388608;           // [16,16,16]

    char* p = (char*)d_ws;
    auto take = [&](size_t n) -> char* {
        char* cur = p; p += (n + 255) & ~(size_t)255; return cur;
    };
    f16_t* Bq = (f16_t*)take(2097152);
    f16_t* Bk = (f16_t*)take(2097152);
    f16_t* Bv = (f16_t*)take(2097152);
    f16_t* Bo = (f16_t*)take(2097152);
    f16_t* Pq16 = (f16_t*)take(16777216);
    f16_t* Pk16 = (f16_t*)take(16777216);
    f16_t* Pv16 = (f16_t*)take(16777216);
    f16_t* xmix = (f16_t*)take(16777216);
    float* part = (float*)take(262144);              // 16x16x256 partials

    pack_w<<<2048, 256, 0, stream>>>(Wq, Wk, Wv, Wo, Bq, Bk, Bv, Bo);

    Gemm3Args ga;
    ga.A[0] = q; ga.A[1] = k; ga.A[2] = v;
    ga.B[0] = Bq; ga.B[1] = Bk; ga.B[2] = Bv;
    ga.bias[0] = bq; ga.bias[1] = bk; ga.bias[2] = bv;
    ga.C16[0] = Pq16; ga.C16[1] = Pk16; ga.C16[2] = Pv16;
    gemm3<<<dim3(64, 8, 3), 256, 0, stream>>>(ga);

    scores_kernel<<<dim3(16, 16), 256, 0, stream>>>(Pq16, Pk16, part);
    mix_kernel<<<512, 256, 0, stream>>>(Pv16, part, beta, attn, xmix);
    gemm_o<<<dim3(64, 8), 256, 0, stream>>>(xmix, Bo, bo, out);
}